// Round 8
// baseline (1071.204 us; speedup 1.0000x reference)
//
#include <hip/hip_runtime.h>
#include <hip/hip_bf16.h>

typedef __attribute__((ext_vector_type(8))) short short8;
typedef __attribute__((ext_vector_type(4))) float float4v;
typedef __attribute__((ext_vector_type(4))) int int4v;

__device__ __forceinline__ float sigmoidf_(float x) {
  return __fdividef(1.f, 1.f + __expf(-x));
}
__device__ __forceinline__ float tanhf_(float x) {
  float e = __expf(2.f * x);
  return 1.f - __fdividef(2.f, e + 1.f);
}
__device__ __forceinline__ float bflo(unsigned int v) {
  return __uint_as_float(v << 16);
}
__device__ __forceinline__ float bfhi(unsigned int v) {
  return __uint_as_float(v & 0xffff0000u);
}
// barrier that waits only LDS counts (h ordering) -- skips the vmcnt(0) drain
__device__ __forceinline__ void barrier_lgkm() {
  asm volatile("s_waitcnt lgkmcnt(0)\n\ts_barrier" ::: "memory");
}

__device__ __forceinline__ unsigned int pack4_(float4 v, float inv) {
  int b0 = (int)rintf(v.x * inv), b1 = (int)rintf(v.y * inv);
  int b2 = (int)rintf(v.z * inv), b3 = (int)rintf(v.w * inv);
  return (unsigned int)((b0 & 0xff) | ((b1 & 0xff) << 8) | ((b2 & 0xff) << 16) |
                        ((b3 & 0xff) << 24));
}

// select component rr (runtime 0..3) from an int4v with literal indices only
__device__ __forceinline__ int sel4_(int4v v, int rr) {
  int a = (rr & 1) ? v[1] : v[0];
  int b = (rr & 1) ? v[3] : v[2];
  return (rr & 2) ? b : a;
}

// ---------------------------------------------------------------------------
// Kernel Q: one-time int8 weight quantization. One wave per gate row.
// wq layout: row-major, 64 u32 (256 i8 along K) per gate-row.
// ---------------------------------------------------------------------------
__global__ __launch_bounds__(256) void wquant_kernel(
    const float* __restrict__ whh_f, const float* __restrict__ whh_b,
    unsigned int* __restrict__ wq, float* __restrict__ wsc) {
  const int wave_g = blockIdx.x * 4 + (threadIdx.x >> 6);
  const int lane = threadIdx.x & 63;
  const int dir = wave_g >> 10, row = wave_g & 1023;
  const float* __restrict__ src = (dir ? whh_b : whh_f) + (size_t)row * 256;
  float4 v = ((const float4*)src)[lane];
  float mx = fmaxf(fmaxf(fabsf(v.x), fabsf(v.y)), fmaxf(fabsf(v.z), fabsf(v.w)));
#pragma unroll
  for (int k = 32; k >= 1; k >>= 1) mx = fmaxf(mx, __shfl_xor(mx, k, 64));
  float inv = (mx > 0.f) ? __fdividef(127.f, mx) : 0.f;
  wq[(size_t)wave_g * 64 + lane] = pack4_(v, inv);
  if (lane == 0) wsc[wave_g] = (mx > 0.f) ? (mx / (127.f * 127.f)) : 0.f;
}

// ---------------------------------------------------------------------------
// Kernel A: projected embedding tables. M-tile 128.
// Stored at out[m*2048 + dir*1024 + u*4 + gate]  ([row][dir][unit][i,f,g,o]).
// ---------------------------------------------------------------------------
__global__ __launch_bounds__(256) void proj_gemm(
    const float* __restrict__ A, int rowsA, int Kdim, int col_off,
    const float* __restrict__ wf, const float* __restrict__ wb,
    const float* __restrict__ bf1, const float* __restrict__ bf2,
    const float* __restrict__ bb1, const float* __restrict__ bb2,
    __hip_bfloat16* __restrict__ out, int add_bias) {
  __shared__ __align__(16) __hip_bfloat16 As[128][40];
  __shared__ __align__(16) __hip_bfloat16 Bs[256][40];
  const int tid = threadIdx.x;
  const int m0 = blockIdx.x * 128, n0 = blockIdx.y * 256;
  const int lane = tid & 63, wave = tid >> 6;
  const int quad = lane >> 4, lm = lane & 15;
  float4v acc[2][16] = {};
  const int ksteps = (Kdim + 31) >> 5;
  const int r2 = tid >> 1, cbase = (tid & 1) << 4;
  const int rb = tid >> 4, cb = (tid & 15) * 2;
  for (int ks = 0; ks < ksteps; ++ks) {
    const int k0 = ks << 5;
#pragma unroll
    for (int e2 = 0; e2 < 8; ++e2) {
      int kk = k0 + cbase + 2 * e2;
      float b0 = 0.f, b1 = 0.f;
      if (m0 + r2 < rowsA && kk < Kdim) {
        float2 v = *(const float2*)(A + (size_t)(m0 + r2) * Kdim + kk);
        b0 = v.x;
        b1 = v.y;
      }
      As[r2][cbase + 2 * e2] = __float2bfloat16(b0);
      As[r2][cbase + 2 * e2 + 1] = __float2bfloat16(b1);
    }
#pragma unroll
    for (int j = 0; j < 16; ++j) {
      int n = n0 + rb + 16 * j;
      const float* __restrict__ wrow =
          (n < 1024) ? (wf + n * 450 + col_off) : (wb + (n - 1024) * 450 + col_off);
      int kk = k0 + cb;
      float b0 = 0.f, b1 = 0.f;
      if (kk < Kdim) {
        float2 v = *(const float2*)(wrow + kk);
        b0 = v.x;
        b1 = v.y;
      }
      Bs[rb + 16 * j][cb] = __float2bfloat16(b0);
      Bs[rb + 16 * j][cb + 1] = __float2bfloat16(b1);
    }
    __syncthreads();
    short8 af0 = *(const short8*)(&As[wave * 32 + lm][quad * 8]);
    short8 af1 = *(const short8*)(&As[wave * 32 + 16 + lm][quad * 8]);
#pragma unroll
    for (int t = 0; t < 16; ++t) {
      short8 bf = *(const short8*)(&Bs[t * 16 + lm][quad * 8]);
      acc[0][t] = __builtin_amdgcn_mfma_f32_16x16x32_bf16(af0, bf, acc[0][t], 0, 0, 0);
      acc[1][t] = __builtin_amdgcn_mfma_f32_16x16x32_bf16(af1, bf, acc[1][t], 0, 0, 0);
    }
    __syncthreads();
  }
#pragma unroll
  for (int mg = 0; mg < 2; ++mg) {
#pragma unroll
    for (int t = 0; t < 16; ++t) {
#pragma unroll
      for (int rr = 0; rr < 4; ++rr) {
        int m = m0 + wave * 32 + mg * 16 + quad * 4 + rr;
        int col = n0 + t * 16 + lm;
        if (m < rowsA) {
          float v = acc[mg][t][rr];
          if (add_bias)
            v += (col < 1024) ? (bf1[col] + bf2[col]) : (bb1[col - 1024] + bb2[col - 1024]);
          int dir = col >> 10, rq = col & 1023;
          int gate = rq >> 8, u = rq & 255;
          out[m * 2048 + dir * 1024 + u * 4 + gate] = __float2bfloat16(v);
        }
      }
    }
  }
}

// ---------------------------------------------------------------------------
// Kernel P: pre-sum pinyin + tag projections: pg[p*20+g] = pin[p] + tag[g].
// ---------------------------------------------------------------------------
__global__ __launch_bounds__(256) void pgsum_kernel(
    const __hip_bfloat16* __restrict__ pin, const __hip_bfloat16* __restrict__ tag,
    __hip_bfloat16* __restrict__ pg) {
  const int r = blockIdx.x;
  const int p = r / 20, g = r - p * 20;
  const int i = threadIdx.x;  // 256 threads x 8 bf16 = 2048
  const short8 va = *(const short8*)(pin + (size_t)p * 2048 + i * 8);
  const short8 vb = *(const short8*)(tag + (size_t)g * 2048 + i * 8);
  short8 vo;
#pragma unroll
  for (int j = 0; j < 8; ++j) {
    float a = __uint_as_float(((unsigned)(unsigned short)va[j]) << 16);
    float b = __uint_as_float(((unsigned)(unsigned short)vb[j]) << 16);
    __hip_bfloat16 o = __float2bfloat16(a + b);
    vo[j] = *(short*)&o;
  }
  *(short8*)(pg + (size_t)r * 2048 + i * 8) = vo;
}

// ---------------------------------------------------------------------------
// Kernel B (R21): 16-wave (1024-thread) MFMA recurrence, 4 waves/SIMD.
// Model-B diagnosis: at 2 waves/SIMD the MFMA pipe was only ~72% fed (per-
// MFMA effective ~32cy vs 20.4 dense; 64x32+480+300 = 2828 ~= 2834 measured;
// explains the R19 rotation's small gain and R20 setprio null). 4 issuing
// waves/SIMD interleave to re-approach the dense rate.
// Partition: wave w owns units [w*16, w*16+16) for ALL 4 gates = 4 M-tiles
// x 4 K-tiles = 16 MFMAs/wave; gate combine stays wave-local. Lane (quad,
// lm): unit = w*16 + quad*4 + (lm&3); lm<4 lanes are writers (4x redundant
// gate math across lm groups -- SIMT-free). Register budget engineered to
// the 128-cap 4 waves/SIMD requires: Wf 64 + acc 16 + Bv 16 (split-preload:
// kt01 post-barrier, kt23 at loop top hidden under kt01's MFMAs) ~= 125.
// hist ring + flush DROPPED: writer lanes store bf16 h directly to h_glob
// (32B/wave contiguous, fire-and-forget) -- one barrier per step, no LDS
// hist traffic. Numerics identical (exact i8 MFMA).
// ---------------------------------------------------------------------------
template <int USE_PG>
__global__ __launch_bounds__(1024, 4) void lstm_kernel(
    const unsigned int* __restrict__ wq, const float* __restrict__ wsc,
    const int* __restrict__ x, const int* __restrict__ ptags, const int* __restrict__ gtags,
    const char* __restrict__ char_proj, const char* __restrict__ pin_proj,
    const char* __restrict__ tag_proj, const char* __restrict__ pg_proj,
    __hip_bfloat16* __restrict__ h_out) {
  extern __shared__ __align__(16) char smem[];
  char* hqb = smem;  // 2 x 272 (256 i8 h + pad)

  const int tid = threadIdx.x;
  const int w = tid >> 6, lane = tid & 63;
  const int quad = lane >> 4, lm = lane & 15;
  const int rr = lm & 3;  // runtime, used with literal idx only (sel4_)
  const int unit = w * 16 + quad * 4 + rr;
  const int chain = blockIdx.x;
  const int dir = chain >> 7;
  const int b = chain & 127;
  const int boff = b * 512;

  if (tid < 34) ((uint4*)hqb)[tid] = make_uint4(0, 0, 0, 0);

  // weight fragments (MFMA A): Wf[g][kt], row = g*256 + w*16 + lm
  const unsigned int* __restrict__ wqd = wq + (size_t)dir * 65536;
  int4v Wf[4][4];
#pragma unroll
  for (int g = 0; g < 4; ++g) {
    const int row = g * 256 + w * 16 + lm;
#pragma unroll
    for (int kt = 0; kt < 4; ++kt)
      Wf[g][kt] = *(const int4v*)(wqd + row * 64 + kt * 16 + quad * 4);
  }
  float sc4[4];
#pragma unroll
  for (int g = 0; g < 4; ++g) sc4[g] = wsc[dir * 1024 + g * 256 + unit];
  __syncthreads();

  const int pre_off = dir * 2048 + unit * 8;  // byte offset into proj rows
  float cst = 0.f;

  // prefetch rotation: indices 2 steps ahead (scalar), gathers 1 step ahead
  int t_cur = dir ? 511 : 0;
  int t_nxt = dir ? 510 : 1;
  uint2 vc, vp, vg;
  int xn, pgn, pn, gn;
  {
    int xc = x[boff + t_cur], pc = ptags[boff + t_cur], gc = gtags[boff + t_cur];
    vc = *(const uint2*)(char_proj + (size_t)xc * 4096 + pre_off);
    if (USE_PG) {
      vp = *(const uint2*)(pg_proj + (size_t)(pc * 20 + gc) * 4096 + pre_off);
    } else {
      vp = *(const uint2*)(pin_proj + (size_t)pc * 4096 + pre_off);
      vg = *(const uint2*)(tag_proj + (size_t)gc * 4096 + pre_off);
    }
    xn = x[boff + t_nxt];
    pn = ptags[boff + t_nxt];
    gn = gtags[boff + t_nxt];
    if (USE_PG) pgn = pn * 20 + gn;
  }

  // prologue: Bv kt=0,1 from buffer 0 (h(-1) = 0); kt=2,3 read at loop top
  int4v Bv0, Bv1, Bv2, Bv3;
  Bv0 = *(const int4v*)(hqb + 0 * 64 + quad * 16);
  Bv1 = *(const int4v*)(hqb + 1 * 64 + quad * 16);

  for (int s = 0; s < 512; ++s) {
    const int cur = s & 1, nxt = cur ^ 1;
    // Bv kt=2,3 from current buffer (latency hides under kt0/kt1 MFMAs)
    Bv2 = *(const int4v*)(hqb + cur * 272 + 2 * 64 + quad * 16);
    Bv3 = *(const int4v*)(hqb + cur * 272 + 3 * 64 + quad * 16);

    const uint2 cv = vc, pv = vp, gv = vg;
    const int t_fut = dir ? (t_nxt > 0 ? t_nxt - 1 : 0) : (t_nxt < 511 ? t_nxt + 1 : 511);
    // issue next-step gathers + next-next indices (independent of MFMA)
    vc = *(const uint2*)(char_proj + (size_t)xn * 4096 + pre_off);
    if (USE_PG) {
      vp = *(const uint2*)(pg_proj + (size_t)pgn * 4096 + pre_off);
    } else {
      vp = *(const uint2*)(pin_proj + (size_t)pn * 4096 + pre_off);
      vg = *(const uint2*)(tag_proj + (size_t)gn * 4096 + pre_off);
    }
    xn = x[boff + t_fut];
    pn = ptags[boff + t_fut];
    gn = gtags[boff + t_fut];
    if (USE_PG) pgn = pn * 20 + gn;

    // 16 MFMAs: 4 gates x 4 K-tiles (kt01 use preloaded Bv, kt23 just-read)
    int4v acc[4] = {};
    __builtin_amdgcn_s_setprio(1);
#pragma unroll
    for (int g = 0; g < 4; ++g)
      acc[g] = __builtin_amdgcn_mfma_i32_16x16x64_i8(Wf[g][0], Bv0, acc[g], 0, 0, 0);
#pragma unroll
    for (int g = 0; g < 4; ++g)
      acc[g] = __builtin_amdgcn_mfma_i32_16x16x64_i8(Wf[g][1], Bv1, acc[g], 0, 0, 0);
#pragma unroll
    for (int g = 0; g < 4; ++g)
      acc[g] = __builtin_amdgcn_mfma_i32_16x16x64_i8(Wf[g][2], Bv2, acc[g], 0, 0, 0);
#pragma unroll
    for (int g = 0; g < 4; ++g)
      acc[g] = __builtin_amdgcn_mfma_i32_16x16x64_i8(Wf[g][3], Bv3, acc[g], 0, 0, 0);
    __builtin_amdgcn_s_setprio(0);

    // gate math for this lane's unit (4x redundant across lm groups)
    int ai = sel4_(acc[0], rr);
    int af = sel4_(acc[1], rr);
    int ag = sel4_(acc[2], rr);
    int ao = sel4_(acc[3], rr);
    float gi, gf, gg, go;
    if (USE_PG) {
      gi = bflo(cv.x) + bflo(pv.x) + (float)ai * sc4[0];
      gf = bfhi(cv.x) + bfhi(pv.x) + (float)af * sc4[1];
      gg = bflo(cv.y) + bflo(pv.y) + (float)ag * sc4[2];
      go = bfhi(cv.y) + bfhi(pv.y) + (float)ao * sc4[3];
    } else {
      gi = bflo(cv.x) + bflo(pv.x) + bflo(gv.x) + (float)ai * sc4[0];
      gf = bfhi(cv.x) + bfhi(pv.x) + bfhi(gv.x) + (float)af * sc4[1];
      gg = bflo(cv.y) + bflo(pv.y) + bflo(gv.y) + (float)ag * sc4[2];
      go = bfhi(cv.y) + bfhi(pv.y) + bfhi(gv.y) + (float)ao * sc4[3];
    }
    cst = sigmoidf_(gf) * cst + sigmoidf_(gi) * tanhf_(gg);
    float hval = sigmoidf_(go) * tanhf_(cst);
    if (lm < 4) {  // one writer lane per unit
      ((signed char*)hqb)[nxt * 272 + unit] = (signed char)(int)rintf(hval * 127.f);
      // direct bf16 store (32B contiguous per wave), fire-and-forget
      h_out[(size_t)(chain * 512 + t_cur) * 256 + unit] = __float2bfloat16(hval);
    }
    barrier_lgkm();
    // read Bv kt=0,1 for step s+1 immediately (latency hides under loop tail)
    Bv0 = *(const int4v*)(hqb + nxt * 272 + 0 * 64 + quad * 16);
    Bv1 = *(const int4v*)(hqb + nxt * 272 + 1 * 64 + quad * 16);
    t_cur = t_nxt;
    t_nxt = t_fut;
  }
}

// ---------------------------------------------------------------------------
// Kernel C: emissions GEMM. em[b*512+t][k] = Hcat[n]·w_out[k] + b_out[k]
// ---------------------------------------------------------------------------
__global__ __launch_bounds__(256) void emis_kernel(
    const __hip_bfloat16* __restrict__ h_glob, const float* __restrict__ w_out,
    const float* __restrict__ b_out, float* __restrict__ em) {
  __shared__ __align__(16) __hip_bfloat16 As[64][40];
  __shared__ __align__(16) __hip_bfloat16 Bs[32][40];
  const int tid = threadIdx.x;
  const int n0 = blockIdx.x * 64;
  const int lane = tid & 63, wave = tid >> 6, quad = lane >> 4, lm = lane & 15;
  float4v acc[2] = {};
  const int r = tid >> 2, c0 = (tid & 3) << 3;
  const int rb = tid >> 3, cb = (tid & 7) << 2;
  for (int ks = 0; ks < 16; ++ks) {
    const int j0 = ks * 32;
    const int dirk = j0 >> 8, jin = j0 & 255;
    const int n = n0 + r, bb = n >> 9, tt = n & 511;
    const uint4* src =
        (const uint4*)(h_glob + ((size_t)(dirk * 128 + bb) * 512 + tt) * 256 + jin + c0);
    *(uint4*)(&As[r][c0]) = *src;
#pragma unroll
    for (int e = 0; e < 4; ++e) {
      float v = (rb < 20) ? w_out[rb * 512 + j0 + cb + e] : 0.f;
      Bs[rb][cb + e] = __float2bfloat16(v);
    }
    __syncthreads();
    short8 af = *(const short8*)(&As[wave * 16 + lm][quad * 8]);
#pragma unroll
    for (int t2 = 0; t2 < 2; ++t2) {
      short8 bf = *(const short8*)(&Bs[t2 * 16 + lm][quad * 8]);
      acc[t2] = __builtin_amdgcn_mfma_f32_16x16x32_bf16(af, bf, acc[t2], 0, 0, 0);
    }
    __syncthreads();
  }
#pragma unroll
  for (int t2 = 0; t2 < 2; ++t2) {
#pragma unroll
    for (int rr = 0; rr < 4; ++rr) {
      int col = t2 * 16 + lm;
      if (col < 20) {
        int n = n0 + wave * 16 + quad * 4 + rr;
        em[(size_t)n * 20 + col] = acc[t2][rr] + b_out[col];
      }
    }
  }
}

// ---------------------------------------------------------------------------
// Kernel D: CRF forward NLL. 1 wave per batch element, readlane broadcast.
// ---------------------------------------------------------------------------
__global__ __launch_bounds__(64) void crf_kernel(
    const float* __restrict__ em, const int* __restrict__ y,
    const float* __restrict__ start_trans, const float* __restrict__ end_trans,
    const float* __restrict__ trans, float* __restrict__ partials) {
  const int b = blockIdx.x;
  const int lane = threadIdx.x;
  const int jj = lane < 20 ? lane : 19;
  const bool act = lane < 20;
  const float* __restrict__ emb = em + (size_t)b * 512 * 20;
  const int* __restrict__ yb = y + b * 512;

  float s_part = 0.f;
#pragma unroll
  for (int i = 0; i < 8; ++i) {
    int t = lane + 64 * i;
    int yc = yb[t];
    float v = emb[t * 20 + yc];
    v += (t == 0) ? start_trans[yc] : trans[yb[t - 1] * 20 + yc];
    s_part += v;
  }
#pragma unroll
  for (int k = 32; k >= 1; k >>= 1) s_part += __shfl_xor(s_part, k, 64);
  float score = s_part + end_trans[yb[511]];

  float ET[20];
#pragma unroll
  for (int i = 0; i < 20; ++i) ET[i] = __expf(trans[i * 20 + jj]);
  float alpha = act ? (start_trans[jj] + emb[jj]) : -1e30f;
  float P = alpha;
#pragma unroll
  for (int k = 32; k >= 1; k >>= 1) P = fmaxf(P, __shfl_xor(P, k, 64));

  float eC = emb[1 * 20 + jj];
  float eN = emb[2 * 20 + jj];
  for (int t = 1; t < 512; ++t) {
    if ((t & 15) == 0) {
      P = alpha;
#pragma unroll
      for (int k = 32; k >= 1; k >>= 1) P = fmaxf(P, __shfl_xor(P, k, 64));
    }
    float ex = __expf(alpha - P);
    float s0 = 0.f, s1 = 0.f;
#pragma unroll
    for (int i = 0; i < 20; i += 2) {
      float e0 = __int_as_float(__builtin_amdgcn_readlane(__float_as_int(ex), i));
      float e1 = __int_as_float(__builtin_amdgcn_readlane(__float_as_int(ex), i + 1));
      s0 = fmaf(e0, ET[i], s0);
      s1 = fmaf(e1, ET[i + 1], s1);
    }
    int tf = t + 2 < 512 ? t + 2 : 511;
    float eF = emb[tf * 20 + jj];
    if (act) alpha = P + __logf(s0 + s1) + eC;
    eC = eN;
    eN = eF;
  }
  float v = act ? (alpha + end_trans[jj]) : -1e30f;
  float Pz = v;
#pragma unroll
  for (int k = 32; k >= 1; k >>= 1) Pz = fmaxf(Pz, __shfl_xor(Pz, k, 64));
  float e2 = __expf(v - Pz);
#pragma unroll
  for (int k = 32; k >= 1; k >>= 1) e2 += __shfl_xor(e2, k, 64);
  float logZ = Pz + __logf(e2);
  if (lane == 0) partials[b] = logZ - score;
}

__global__ __launch_bounds__(128) void reduce_kernel(const float* __restrict__ partials,
                                                     float* __restrict__ out) {
  const int tid = threadIdx.x;
  float v = partials[tid];
#pragma unroll
  for (int k = 32; k >= 1; k >>= 1) v += __shfl_xor(v, k, 64);
  __shared__ float tmp[2];
  if ((tid & 63) == 0) tmp[tid >> 6] = v;
  __syncthreads();
  if (tid == 0) out[0] = tmp[0] + tmp[1];
}

// ---------------------------------------------------------------------------
extern "C" void kernel_launch(void* const* d_in, const int* in_sizes, int n_in,
                              void* d_out, int out_size, void* d_ws, size_t ws_size,
                              hipStream_t stream) {
  const int* x = (const int*)d_in[0];
  const int* y = (const int*)d_in[1];
  const int* pre_tags = (const int*)d_in[2];
  const int* pinyin_tags = (const int*)d_in[3];
  const float* char_emb = (const float*)d_in[5];
  const float* tag_emb = (const float*)d_in[6];
  const float* pinyin_emb = (const float*)d_in[7];
  const float* w_ih_f = (const float*)d_in[8];
  const float* w_hh_f = (const float*)d_in[9];
  const float* b_ih_f = (const float*)d_in[10];
  const float* b_hh_f = (const float*)d_in[11];
  const float* w_ih_b = (const float*)d_in[12];
  const float* w_hh_b = (const float*)d_in[13];
  const float* b_ih_b = (const float*)d_in[14];
  const float* b_hh_b = (const float*)d_in[15];
  const float* w_out = (const float*)d_in[16];
  const float* b_out = (const float*)d_in[17];
  const float* start_trans = (const float*)d_in[18];
  const float* end_trans = (const float*)d_in[19];
  const float* trans = (const float*)d_in[20];

  char* ws = (char*)d_ws;
  __hip_bfloat16* char_proj = (__hip_bfloat16*)(ws);            // 10002*2048*2 = 40968192
  __hip_bfloat16* pin_proj = (__hip_bfloat16*)(ws + 40968192);  // 500*2048*2  = 2048000
  __hip_bfloat16* tag_proj = (__hip_bfloat16*)(ws + 43016192);  // 20*2048*2   = 81920
  __hip_bfloat16* h_glob = (__hip_bfloat16*)(ws + 43098112);    // 2*128*512*256*2 = 67108864
  float* em = (float*)(ws + 110206976);                         // 65536*20*4 = 5242880
  float* partials = (float*)(ws + 115449856);                   // 128*4
  // wq/wsc live inside the em region (em is written only after lstm finishes)
  unsigned int* wq = (unsigned int*)(ws + 110206976);           // 2*1024*64*4 = 524288
  float* wsc = (float*)(ws + 110206976 + 524288);               // 2048*4
  // optional presummed pinyin+tag table (runtime-gated on ws_size)
  __hip_bfloat16* pg_proj = (__hip_bfloat16*)(ws + 115450368);  // 10000*2048*2 = 40960000
  const bool use_pg = ws_size >= (size_t)115450368 + 40960000;

  wquant_kernel<<<512, 256, 0, stream>>>(w_hh_f, w_hh_b, wq, wsc);

  proj_gemm<<<dim3(79, 8), 256, 0, stream>>>(char_emb, 10002, 300, 0, w_ih_f, w_ih_b,
                                             nullptr, nullptr, nullptr, nullptr, char_proj, 0);
  proj_gemm<<<dim3(4, 8), 256, 0, stream>>>(pinyin_emb, 500, 100, 300, w_ih_f, w_ih_b,
                                            nullptr, nullptr, nullptr, nullptr, pin_proj, 0);
  proj_gemm<<<dim3(1, 8), 256, 0, stream>>>(tag_emb, 20, 50, 400, w_ih_f, w_ih_b,
                                            b_ih_f, b_hh_f, b_ih_b, b_hh_b, tag_proj, 1);
  if (use_pg) pgsum_kernel<<<10000, 256, 0, stream>>>(pin_proj, tag_proj, pg_proj);

  const int lstm_lds = 1024;  // 544 hq double buffer (padded)
  if (use_pg) {
    hipFuncSetAttribute((const void*)lstm_kernel<1>, hipFuncAttributeMaxDynamicSharedMemorySize,
                        lstm_lds);
    lstm_kernel<1><<<256, 1024, lstm_lds, stream>>>(wq, wsc, x, pinyin_tags, pre_tags,
                                                    (const char*)char_proj, (const char*)pin_proj,
                                                    (const char*)tag_proj, (const char*)pg_proj,
                                                    h_glob);
  } else {
    hipFuncSetAttribute((const void*)lstm_kernel<0>, hipFuncAttributeMaxDynamicSharedMemorySize,
                        lstm_lds);
    lstm_kernel<0><<<256, 1024, lstm_lds, stream>>>(wq, wsc, x, pinyin_tags, pre_tags,
                                                    (const char*)char_proj, (const char*)pin_proj,
                                                    (const char*)tag_proj, (const char*)pg_proj,
                                                    h_glob);
  }

  emis_kernel<<<1024, 256, 0, stream>>>(h_glob, w_out, b_out, em);
  crf_kernel<<<128, 64, 0, stream>>>(em, y, start_trans, end_trans, trans, partials);
  reduce_kernel<<<1, 128, 0, stream>>>(partials, (float*)d_out);
}

// Round 9
// 947.001 us; speedup vs baseline: 1.1312x; 1.1312x over previous
//
#include <hip/hip_runtime.h>
#include <hip/hip_bf16.h>

typedef __attribute__((ext_vector_type(8))) short short8;
typedef __attribute__((ext_vector_type(4))) float float4v;
typedef __attribute__((ext_vector_type(4))) int int4v;

__device__ __forceinline__ float sigmoidf_(float x) {
  return __fdividef(1.f, 1.f + __expf(-x));
}
__device__ __forceinline__ float tanhf_(float x) {
  float e = __expf(2.f * x);
  return 1.f - __fdividef(2.f, e + 1.f);
}
__device__ __forceinline__ float bflo(unsigned int v) {
  return __uint_as_float(v << 16);
}
__device__ __forceinline__ float bfhi(unsigned int v) {
  return __uint_as_float(v & 0xffff0000u);
}
// barrier that waits only LDS counts (h ordering) -- skips the vmcnt(0) drain
__device__ __forceinline__ void barrier_lgkm() {
  asm volatile("s_waitcnt lgkmcnt(0)\n\ts_barrier" ::: "memory");
}

__device__ __forceinline__ unsigned int pack4_(float4 v, float inv) {
  int b0 = (int)rintf(v.x * inv), b1 = (int)rintf(v.y * inv);
  int b2 = (int)rintf(v.z * inv), b3 = (int)rintf(v.w * inv);
  return (unsigned int)((b0 & 0xff) | ((b1 & 0xff) << 8) | ((b2 & 0xff) << 16) |
                        ((b3 & 0xff) << 24));
}

// select component rr (runtime 0..3) from an int4v with literal indices only
__device__ __forceinline__ int sel4_(int4v v, int rr) {
  int a = (rr & 1) ? v[1] : v[0];
  int b = (rr & 1) ? v[3] : v[2];
  return (rr & 2) ? b : a;
}

// ---------------------------------------------------------------------------
// Kernel Q: one-time int8 weight quantization. One wave per gate row.
// wq layout: row-major, 64 u32 (256 i8 along K) per gate-row.
// ---------------------------------------------------------------------------
__global__ __launch_bounds__(256) void wquant_kernel(
    const float* __restrict__ whh_f, const float* __restrict__ whh_b,
    unsigned int* __restrict__ wq, float* __restrict__ wsc) {
  const int wave_g = blockIdx.x * 4 + (threadIdx.x >> 6);
  const int lane = threadIdx.x & 63;
  const int dir = wave_g >> 10, row = wave_g & 1023;
  const float* __restrict__ src = (dir ? whh_b : whh_f) + (size_t)row * 256;
  float4 v = ((const float4*)src)[lane];
  float mx = fmaxf(fmaxf(fabsf(v.x), fabsf(v.y)), fmaxf(fabsf(v.z), fabsf(v.w)));
#pragma unroll
  for (int k = 32; k >= 1; k >>= 1) mx = fmaxf(mx, __shfl_xor(mx, k, 64));
  float inv = (mx > 0.f) ? __fdividef(127.f, mx) : 0.f;
  wq[(size_t)wave_g * 64 + lane] = pack4_(v, inv);
  if (lane == 0) wsc[wave_g] = (mx > 0.f) ? (mx / (127.f * 127.f)) : 0.f;
}

// ---------------------------------------------------------------------------
// Kernel A: projected embedding tables. M-tile 128.
// Stored at out[m*2048 + dir*1024 + u*4 + gate]  ([row][dir][unit][i,f,g,o]).
// ---------------------------------------------------------------------------
__global__ __launch_bounds__(256) void proj_gemm(
    const float* __restrict__ A, int rowsA, int Kdim, int col_off,
    const float* __restrict__ wf, const float* __restrict__ wb,
    const float* __restrict__ bf1, const float* __restrict__ bf2,
    const float* __restrict__ bb1, const float* __restrict__ bb2,
    __hip_bfloat16* __restrict__ out, int add_bias) {
  __shared__ __align__(16) __hip_bfloat16 As[128][40];
  __shared__ __align__(16) __hip_bfloat16 Bs[256][40];
  const int tid = threadIdx.x;
  const int m0 = blockIdx.x * 128, n0 = blockIdx.y * 256;
  const int lane = tid & 63, wave = tid >> 6;
  const int quad = lane >> 4, lm = lane & 15;
  float4v acc[2][16] = {};
  const int ksteps = (Kdim + 31) >> 5;
  const int r2 = tid >> 1, cbase = (tid & 1) << 4;
  const int rb = tid >> 4, cb = (tid & 15) * 2;
  for (int ks = 0; ks < ksteps; ++ks) {
    const int k0 = ks << 5;
#pragma unroll
    for (int e2 = 0; e2 < 8; ++e2) {
      int kk = k0 + cbase + 2 * e2;
      float b0 = 0.f, b1 = 0.f;
      if (m0 + r2 < rowsA && kk < Kdim) {
        float2 v = *(const float2*)(A + (size_t)(m0 + r2) * Kdim + kk);
        b0 = v.x;
        b1 = v.y;
      }
      As[r2][cbase + 2 * e2] = __float2bfloat16(b0);
      As[r2][cbase + 2 * e2 + 1] = __float2bfloat16(b1);
    }
#pragma unroll
    for (int j = 0; j < 16; ++j) {
      int n = n0 + rb + 16 * j;
      const float* __restrict__ wrow =
          (n < 1024) ? (wf + n * 450 + col_off) : (wb + (n - 1024) * 450 + col_off);
      int kk = k0 + cb;
      float b0 = 0.f, b1 = 0.f;
      if (kk < Kdim) {
        float2 v = *(const float2*)(wrow + kk);
        b0 = v.x;
        b1 = v.y;
      }
      Bs[rb + 16 * j][cb] = __float2bfloat16(b0);
      Bs[rb + 16 * j][cb + 1] = __float2bfloat16(b1);
    }
    __syncthreads();
    short8 af0 = *(const short8*)(&As[wave * 32 + lm][quad * 8]);
    short8 af1 = *(const short8*)(&As[wave * 32 + 16 + lm][quad * 8]);
#pragma unroll
    for (int t = 0; t < 16; ++t) {
      short8 bf = *(const short8*)(&Bs[t * 16 + lm][quad * 8]);
      acc[0][t] = __builtin_amdgcn_mfma_f32_16x16x32_bf16(af0, bf, acc[0][t], 0, 0, 0);
      acc[1][t] = __builtin_amdgcn_mfma_f32_16x16x32_bf16(af1, bf, acc[1][t], 0, 0, 0);
    }
    __syncthreads();
  }
#pragma unroll
  for (int mg = 0; mg < 2; ++mg) {
#pragma unroll
    for (int t = 0; t < 16; ++t) {
#pragma unroll
      for (int rr = 0; rr < 4; ++rr) {
        int m = m0 + wave * 32 + mg * 16 + quad * 4 + rr;
        int col = n0 + t * 16 + lm;
        if (m < rowsA) {
          float v = acc[mg][t][rr];
          if (add_bias)
            v += (col < 1024) ? (bf1[col] + bf2[col]) : (bb1[col - 1024] + bb2[col - 1024]);
          int dir = col >> 10, rq = col & 1023;
          int gate = rq >> 8, u = rq & 255;
          out[m * 2048 + dir * 1024 + u * 4 + gate] = __float2bfloat16(v);
        }
      }
    }
  }
}

// ---------------------------------------------------------------------------
// Kernel P: pre-sum pinyin + tag projections: pg[p*20+g] = pin[p] + tag[g].
// ---------------------------------------------------------------------------
__global__ __launch_bounds__(256) void pgsum_kernel(
    const __hip_bfloat16* __restrict__ pin, const __hip_bfloat16* __restrict__ tag,
    __hip_bfloat16* __restrict__ pg) {
  const int r = blockIdx.x;
  const int p = r / 20, g = r - p * 20;
  const int i = threadIdx.x;  // 256 threads x 8 bf16 = 2048
  const short8 va = *(const short8*)(pin + (size_t)p * 2048 + i * 8);
  const short8 vb = *(const short8*)(tag + (size_t)g * 2048 + i * 8);
  short8 vo;
#pragma unroll
  for (int j = 0; j < 8; ++j) {
    float a = __uint_as_float(((unsigned)(unsigned short)va[j]) << 16);
    float b = __uint_as_float(((unsigned)(unsigned short)vb[j]) << 16);
    __hip_bfloat16 o = __float2bfloat16(a + b);
    vo[j] = *(short*)&o;
  }
  *(short8*)(pg + (size_t)r * 2048 + i * 8) = vo;
}

// ---------------------------------------------------------------------------
// Kernel B (R22): champion structure (R19: 512 thr, 8 waves, rotated Bv
// preload, PG gathers) with measured waste removed:
//  - acc zero-init folded into kt=0 MFMA via hoisted kZero (saves ~32
//    v_mov = 64cy/step),
//  - hist ring + 16-step flush dropped; writer lanes store bf16 h DIRECTLY
//    to h_out, placed after the barrier + Bv issues (store also covers Bv
//    LDS latency),
//  - token indices computed from the uniform loop index (affine formula) --
//    drops the t_cur/t_nxt/t_fut VGPR rotation,
//  - no setprio (R19 599 vs R20 604: null-to-negative).
// R21 post-mortem: 4 waves/SIMD retry spilled again (VGPR=60, 31ms scratch
// first dispatch); all register-safe 16-wave variants are LDS-pipe-bound
// (Wf-from-LDS needs ~1500cy/step > 1306 MFMA). 2 waves/SIMD is the
// structure's operating point; lstm ~600us is its plateau.
// ---------------------------------------------------------------------------
template <int USE_PG>
__global__ __launch_bounds__(512, 2) void lstm_kernel(
    const unsigned int* __restrict__ wq, const float* __restrict__ wsc,
    const int* __restrict__ x, const int* __restrict__ ptags, const int* __restrict__ gtags,
    const char* __restrict__ char_proj, const char* __restrict__ pin_proj,
    const char* __restrict__ tag_proj, const char* __restrict__ pg_proj,
    __hip_bfloat16* __restrict__ h_out) {
  extern __shared__ __align__(16) char smem[];
  char* hqb = smem;  // 2 x 272 (256 i8 h + pad)

  const int tid = threadIdx.x;
  const int w = tid >> 6, lane = tid & 63;
  const int quad = lane >> 4, lm = lane & 15;
  const int sel = lm >> 1;                // 0..7
  const int mt = sel >> 2, rr = sel & 3;  // runtime, used with literal idx only
  const int unit = w * 32 + mt * 16 + quad * 4 + rr;
  const int chain = blockIdx.x;
  const int dir = chain >> 7;
  const int b = chain & 127;
  const int boff = b * 512;

  if (tid < 34) ((uint4*)hqb)[tid] = make_uint4(0, 0, 0, 0);

  // weight fragments (MFMA A): Wf[g][m][kt], row = g*256 + w*32 + m*16 + lm
  const unsigned int* __restrict__ wqd = wq + (size_t)dir * 65536;
  int4v Wf[4][2][4];
#pragma unroll
  for (int g = 0; g < 4; ++g)
#pragma unroll
    for (int m = 0; m < 2; ++m) {
      const int row = g * 256 + w * 32 + m * 16 + lm;
#pragma unroll
      for (int kt = 0; kt < 4; ++kt)
        Wf[g][m][kt] = *(const int4v*)(wqd + row * 64 + kt * 16 + quad * 4);
    }
  float sc4[4];
#pragma unroll
  for (int g = 0; g < 4; ++g) sc4[g] = wsc[dir * 1024 + g * 256 + unit];
  __syncthreads();

  const int pre_off = dir * 2048 + unit * 8;  // byte offset into proj rows
  float cst = 0.f;
  int4v kZero = {0, 0, 0, 0};
  asm volatile("" : "+v"(kZero));  // keep materialized; block rematerialize-per-use

  // prologue: gathers for step 0; indices for step 1
  uint2 vc, vp, vg;
  int xn, pgn, pn, gn;
  {
    const int t0 = dir ? 511 : 0;
    int xc = x[boff + t0], pc = ptags[boff + t0], gc = gtags[boff + t0];
    vc = *(const uint2*)(char_proj + (size_t)xc * 4096 + pre_off);
    if (USE_PG) {
      vp = *(const uint2*)(pg_proj + (size_t)(pc * 20 + gc) * 4096 + pre_off);
    } else {
      vp = *(const uint2*)(pin_proj + (size_t)pc * 4096 + pre_off);
      vg = *(const uint2*)(tag_proj + (size_t)gc * 4096 + pre_off);
    }
    const int t1 = dir ? 510 : 1;
    xn = x[boff + t1];
    pn = ptags[boff + t1];
    gn = gtags[boff + t1];
    if (USE_PG) pgn = pn * 20 + gn;
  }

  // prologue: Bv(0) from buffer 0 (h(-1) = 0)
  int4v Bv[4];
#pragma unroll
  for (int kt = 0; kt < 4; ++kt)
    Bv[kt] = *(const int4v*)(hqb + kt * 64 + quad * 16);

  __hip_bfloat16* __restrict__ hrow = h_out + (size_t)chain * 512 * 256 + unit;

  for (int s = 0; s < 512; ++s) {
    const int nxt = (s & 1) ^ 1;
    const uint2 cv = vc, pv = vp, gv = vg;
    // issue gathers for step s+1 (xn/pgn hold its indices); prefetch s+2 idx
    vc = *(const uint2*)(char_proj + (size_t)xn * 4096 + pre_off);
    if (USE_PG) {
      vp = *(const uint2*)(pg_proj + (size_t)pgn * 4096 + pre_off);
    } else {
      vp = *(const uint2*)(pin_proj + (size_t)pn * 4096 + pre_off);
      vg = *(const uint2*)(tag_proj + (size_t)gn * 4096 + pre_off);
    }
    {
      const int k2 = (s + 2 < 512) ? s + 2 : 511;
      const int t2 = dir ? 511 - k2 : k2;
      xn = x[boff + t2];
      pn = ptags[boff + t2];
      gn = gtags[boff + t2];
      if (USE_PG) pgn = pn * 20 + gn;
    }

    // MFMA with preloaded Bv; kt=0 initializes acc from kZero (no mov burst)
    int4v acc[4][2];
#pragma unroll
    for (int g = 0; g < 4; ++g)
#pragma unroll
      for (int m = 0; m < 2; ++m)
        acc[g][m] = __builtin_amdgcn_mfma_i32_16x16x64_i8(Wf[g][m][0], Bv[0], kZero, 0, 0, 0);
#pragma unroll
    for (int kt = 1; kt < 4; ++kt) {
#pragma unroll
      for (int g = 0; g < 4; ++g)
#pragma unroll
        for (int m = 0; m < 2; ++m)
          acc[g][m] = __builtin_amdgcn_mfma_i32_16x16x64_i8(Wf[g][m][kt], Bv[kt], acc[g][m], 0, 0, 0);
    }

    // gate math: this lane's unit; acc component picked by (mt, rr)
    int ai = mt ? sel4_(acc[0][1], rr) : sel4_(acc[0][0], rr);
    int af = mt ? sel4_(acc[1][1], rr) : sel4_(acc[1][0], rr);
    int ag = mt ? sel4_(acc[2][1], rr) : sel4_(acc[2][0], rr);
    int ao = mt ? sel4_(acc[3][1], rr) : sel4_(acc[3][0], rr);
    float gi, gf, gg, go;
    if (USE_PG) {
      gi = bflo(cv.x) + bflo(pv.x) + (float)ai * sc4[0];
      gf = bfhi(cv.x) + bfhi(pv.x) + (float)af * sc4[1];
      gg = bflo(cv.y) + bflo(pv.y) + (float)ag * sc4[2];
      go = bfhi(cv.y) + bfhi(pv.y) + (float)ao * sc4[3];
    } else {
      gi = bflo(cv.x) + bflo(pv.x) + bflo(gv.x) + (float)ai * sc4[0];
      gf = bfhi(cv.x) + bfhi(pv.x) + bfhi(gv.x) + (float)af * sc4[1];
      gg = bflo(cv.y) + bflo(pv.y) + bflo(gv.y) + (float)ag * sc4[2];
      go = bfhi(cv.y) + bfhi(pv.y) + bfhi(gv.y) + (float)ao * sc4[3];
    }
    cst = sigmoidf_(gf) * cst + sigmoidf_(gi) * tanhf_(gg);
    float hval = sigmoidf_(go) * tanhf_(cst);
    if (!(lm & 1)) {  // even lm lanes cover all 256 units exactly once
      ((signed char*)hqb)[nxt * 272 + unit] = (signed char)(int)rintf(hval * 127.f);
    }
    barrier_lgkm();
    // read Bv for step s+1 IMMEDIATELY; the global h store below covers the
    // LDS latency before the next MFMA block consumes Bv
#pragma unroll
    for (int kt = 0; kt < 4; ++kt)
      Bv[kt] = *(const int4v*)(hqb + nxt * 272 + kt * 64 + quad * 16);
    if (!(lm & 1)) {
      const int tcur = dir ? 511 - s : s;
      hrow[(size_t)tcur * 256] = __float2bfloat16(hval);  // fire-and-forget
    }
  }
}

// ---------------------------------------------------------------------------
// Kernel C: emissions GEMM. em[b*512+t][k] = Hcat[n]·w_out[k] + b_out[k]
// ---------------------------------------------------------------------------
__global__ __launch_bounds__(256) void emis_kernel(
    const __hip_bfloat16* __restrict__ h_glob, const float* __restrict__ w_out,
    const float* __restrict__ b_out, float* __restrict__ em) {
  __shared__ __align__(16) __hip_bfloat16 As[64][40];
  __shared__ __align__(16) __hip_bfloat16 Bs[32][40];
  const int tid = threadIdx.x;
  const int n0 = blockIdx.x * 64;
  const int lane = tid & 63, wave = tid >> 6, quad = lane >> 4, lm = lane & 15;
  float4v acc[2] = {};
  const int r = tid >> 2, c0 = (tid & 3) << 3;
  const int rb = tid >> 3, cb = (tid & 7) << 2;
  for (int ks = 0; ks < 16; ++ks) {
    const int j0 = ks * 32;
    const int dirk = j0 >> 8, jin = j0 & 255;
    const int n = n0 + r, bb = n >> 9, tt = n & 511;
    const uint4* src =
        (const uint4*)(h_glob + ((size_t)(dirk * 128 + bb) * 512 + tt) * 256 + jin + c0);
    *(uint4*)(&As[r][c0]) = *src;
#pragma unroll
    for (int e = 0; e < 4; ++e) {
      float v = (rb < 20) ? w_out[rb * 512 + j0 + cb + e] : 0.f;
      Bs[rb][cb + e] = __float2bfloat16(v);
    }
    __syncthreads();
    short8 af = *(const short8*)(&As[wave * 16 + lm][quad * 8]);
#pragma unroll
    for (int t2 = 0; t2 < 2; ++t2) {
      short8 bf = *(const short8*)(&Bs[t2 * 16 + lm][quad * 8]);
      acc[t2] = __builtin_amdgcn_mfma_f32_16x16x32_bf16(af, bf, acc[t2], 0, 0, 0);
    }
    __syncthreads();
  }
#pragma unroll
  for (int t2 = 0; t2 < 2; ++t2) {
#pragma unroll
    for (int rr = 0; rr < 4; ++rr) {
      int col = t2 * 16 + lm;
      if (col < 20) {
        int n = n0 + wave * 16 + quad * 4 + rr;
        em[(size_t)n * 20 + col] = acc[t2][rr] + b_out[col];
      }
    }
  }
}

// ---------------------------------------------------------------------------
// Kernel D: CRF forward NLL. 1 wave per batch element, readlane broadcast.
// ---------------------------------------------------------------------------
__global__ __launch_bounds__(64) void crf_kernel(
    const float* __restrict__ em, const int* __restrict__ y,
    const float* __restrict__ start_trans, const float* __restrict__ end_trans,
    const float* __restrict__ trans, float* __restrict__ partials) {
  const int b = blockIdx.x;
  const int lane = threadIdx.x;
  const int jj = lane < 20 ? lane : 19;
  const bool act = lane < 20;
  const float* __restrict__ emb = em + (size_t)b * 512 * 20;
  const int* __restrict__ yb = y + b * 512;

  float s_part = 0.f;
#pragma unroll
  for (int i = 0; i < 8; ++i) {
    int t = lane + 64 * i;
    int yc = yb[t];
    float v = emb[t * 20 + yc];
    v += (t == 0) ? start_trans[yc] : trans[yb[t - 1] * 20 + yc];
    s_part += v;
  }
#pragma unroll
  for (int k = 32; k >= 1; k >>= 1) s_part += __shfl_xor(s_part, k, 64);
  float score = s_part + end_trans[yb[511]];

  float ET[20];
#pragma unroll
  for (int i = 0; i < 20; ++i) ET[i] = __expf(trans[i * 20 + jj]);
  float alpha = act ? (start_trans[jj] + emb[jj]) : -1e30f;
  float P = alpha;
#pragma unroll
  for (int k = 32; k >= 1; k >>= 1) P = fmaxf(P, __shfl_xor(P, k, 64));

  float eC = emb[1 * 20 + jj];
  float eN = emb[2 * 20 + jj];
  for (int t = 1; t < 512; ++t) {
    if ((t & 15) == 0) {
      P = alpha;
#pragma unroll
      for (int k = 32; k >= 1; k >>= 1) P = fmaxf(P, __shfl_xor(P, k, 64));
    }
    float ex = __expf(alpha - P);
    float s0 = 0.f, s1 = 0.f;
#pragma unroll
    for (int i = 0; i < 20; i += 2) {
      float e0 = __int_as_float(__builtin_amdgcn_readlane(__float_as_int(ex), i));
      float e1 = __int_as_float(__builtin_amdgcn_readlane(__float_as_int(ex), i + 1));
      s0 = fmaf(e0, ET[i], s0);
      s1 = fmaf(e1, ET[i + 1], s1);
    }
    int tf = t + 2 < 512 ? t + 2 : 511;
    float eF = emb[tf * 20 + jj];
    if (act) alpha = P + __logf(s0 + s1) + eC;
    eC = eN;
    eN = eF;
  }
  float v = act ? (alpha + end_trans[jj]) : -1e30f;
  float Pz = v;
#pragma unroll
  for (int k = 32; k >= 1; k >>= 1) Pz = fmaxf(Pz, __shfl_xor(Pz, k, 64));
  float e2 = __expf(v - Pz);
#pragma unroll
  for (int k = 32; k >= 1; k >>= 1) e2 += __shfl_xor(e2, k, 64);
  float logZ = Pz + __logf(e2);
  if (lane == 0) partials[b] = logZ - score;
}

__global__ __launch_bounds__(128) void reduce_kernel(const float* __restrict__ partials,
                                                     float* __restrict__ out) {
  const int tid = threadIdx.x;
  float v = partials[tid];
#pragma unroll
  for (int k = 32; k >= 1; k >>= 1) v += __shfl_xor(v, k, 64);
  __shared__ float tmp[2];
  if ((tid & 63) == 0) tmp[tid >> 6] = v;
  __syncthreads();
  if (tid == 0) out[0] = tmp[0] + tmp[1];
}

// ---------------------------------------------------------------------------
extern "C" void kernel_launch(void* const* d_in, const int* in_sizes, int n_in,
                              void* d_out, int out_size, void* d_ws, size_t ws_size,
                              hipStream_t stream) {
  const int* x = (const int*)d_in[0];
  const int* y = (const int*)d_in[1];
  const int* pre_tags = (const int*)d_in[2];
  const int* pinyin_tags = (const int*)d_in[3];
  const float* char_emb = (const float*)d_in[5];
  const float* tag_emb = (const float*)d_in[6];
  const float* pinyin_emb = (const float*)d_in[7];
  const float* w_ih_f = (const float*)d_in[8];
  const float* w_hh_f = (const float*)d_in[9];
  const float* b_ih_f = (const float*)d_in[10];
  const float* b_hh_f = (const float*)d_in[11];
  const float* w_ih_b = (const float*)d_in[12];
  const float* w_hh_b = (const float*)d_in[13];
  const float* b_ih_b = (const float*)d_in[14];
  const float* b_hh_b = (const float*)d_in[15];
  const float* w_out = (const float*)d_in[16];
  const float* b_out = (const float*)d_in[17];
  const float* start_trans = (const float*)d_in[18];
  const float* end_trans = (const float*)d_in[19];
  const float* trans = (const float*)d_in[20];

  char* ws = (char*)d_ws;
  __hip_bfloat16* char_proj = (__hip_bfloat16*)(ws);            // 10002*2048*2 = 40968192
  __hip_bfloat16* pin_proj = (__hip_bfloat16*)(ws + 40968192);  // 500*2048*2  = 2048000
  __hip_bfloat16* tag_proj = (__hip_bfloat16*)(ws + 43016192);  // 20*2048*2   = 81920
  __hip_bfloat16* h_glob = (__hip_bfloat16*)(ws + 43098112);    // 2*128*512*256*2 = 67108864
  float* em = (float*)(ws + 110206976);                         // 65536*20*4 = 5242880
  float* partials = (float*)(ws + 115449856);                   // 128*4
  // wq/wsc live inside the em region (em is written only after lstm finishes)
  unsigned int* wq = (unsigned int*)(ws + 110206976);           // 2*1024*64*4 = 524288
  float* wsc = (float*)(ws + 110206976 + 524288);               // 2048*4
  // optional presummed pinyin+tag table (runtime-gated on ws_size)
  __hip_bfloat16* pg_proj = (__hip_bfloat16*)(ws + 115450368);  // 10000*2048*2 = 40960000
  const bool use_pg = ws_size >= (size_t)115450368 + 40960000;

  wquant_kernel<<<512, 256, 0, stream>>>(w_hh_f, w_hh_b, wq, wsc);

  proj_gemm<<<dim3(79, 8), 256, 0, stream>>>(char_emb, 10002, 300, 0, w_ih_f, w_ih_b,
                                             nullptr, nullptr, nullptr, nullptr, char_proj, 0);
  proj_gemm<<<dim3(4, 8), 256, 0, stream>>>(pinyin_emb, 500, 100, 300, w_ih_f, w_ih_b,
                                            nullptr, nullptr, nullptr, nullptr, pin_proj, 0);
  proj_gemm<<<dim3(1, 8), 256, 0, stream>>>(tag_emb, 20, 50, 400, w_ih_f, w_ih_b,
                                            b_ih_f, b_hh_f, b_ih_b, b_hh_b, tag_proj, 1);
  if (use_pg) pgsum_kernel<<<10000, 256, 0, stream>>>(pin_proj, tag_proj, pg_proj);

  const int lstm_lds = 1024;  // 544 hq double buffer (padded)
  if (use_pg) {
    hipFuncSetAttribute((const void*)lstm_kernel<1>, hipFuncAttributeMaxDynamicSharedMemorySize,
                        lstm_lds);
    lstm_kernel<1><<<256, 512, lstm_lds, stream>>>(wq, wsc, x, pinyin_tags, pre_tags,
                                                   (const char*)char_proj, (const char*)pin_proj,
                                                   (const char*)tag_proj, (const char*)pg_proj,
                                                   h_glob);
  } else {
    hipFuncSetAttribute((const void*)lstm_kernel<0>, hipFuncAttributeMaxDynamicSharedMemorySize,
                        lstm_lds);
    lstm_kernel<0><<<256, 512, lstm_lds, stream>>>(wq, wsc, x, pinyin_tags, pre_tags,
                                                   (const char*)char_proj, (const char*)pin_proj,
                                                   (const char*)tag_proj, (const char*)pg_proj,
                                                   h_glob);
  }

  emis_kernel<<<1024, 256, 0, stream>>>(h_glob, w_out, b_out, em);
  crf_kernel<<<128, 64, 0, stream>>>(em, y, start_trans, end_trans, trans, partials);
  reduce_kernel<<<1, 128, 0, stream>>>(partials, (float*)d_out);
}

// Round 10
// 938.370 us; speedup vs baseline: 1.1416x; 1.0092x over previous
//
#include <hip/hip_runtime.h>
#include <hip/hip_bf16.h>

typedef __attribute__((ext_vector_type(8))) short short8;
typedef __attribute__((ext_vector_type(4))) float float4v;
typedef __attribute__((ext_vector_type(4))) int int4v;

__device__ __forceinline__ float sigmoidf_(float x) {
  return __fdividef(1.f, 1.f + __expf(-x));
}
__device__ __forceinline__ float tanhf_(float x) {
  float e = __expf(2.f * x);
  return 1.f - __fdividef(2.f, e + 1.f);
}
__device__ __forceinline__ float bflo(unsigned int v) {
  return __uint_as_float(v << 16);
}
__device__ __forceinline__ float bfhi(unsigned int v) {
  return __uint_as_float(v & 0xffff0000u);
}
// barrier that waits only LDS counts (h ordering) -- skips the vmcnt(0) drain
__device__ __forceinline__ void barrier_lgkm() {
  asm volatile("s_waitcnt lgkmcnt(0)\n\ts_barrier" ::: "memory");
}

__device__ __forceinline__ unsigned int pack4_(float4 v, float inv) {
  int b0 = (int)rintf(v.x * inv), b1 = (int)rintf(v.y * inv);
  int b2 = (int)rintf(v.z * inv), b3 = (int)rintf(v.w * inv);
  return (unsigned int)((b0 & 0xff) | ((b1 & 0xff) << 8) | ((b2 & 0xff) << 16) |
                        ((b3 & 0xff) << 24));
}

// select component rr (runtime 0..3) from an int4v with literal indices only
__device__ __forceinline__ int sel4_(int4v v, int rr) {
  int a = (rr & 1) ? v[1] : v[0];
  int b = (rr & 1) ? v[3] : v[2];
  return (rr & 2) ? b : a;
}

// ---------------------------------------------------------------------------
// Kernel Q: one-time int8 weight quantization. One wave per gate row.
// wq layout: row-major, 64 u32 (256 i8 along K) per gate-row.
// ---------------------------------------------------------------------------
__global__ __launch_bounds__(256) void wquant_kernel(
    const float* __restrict__ whh_f, const float* __restrict__ whh_b,
    unsigned int* __restrict__ wq, float* __restrict__ wsc) {
  const int wave_g = blockIdx.x * 4 + (threadIdx.x >> 6);
  const int lane = threadIdx.x & 63;
  const int dir = wave_g >> 10, row = wave_g & 1023;
  const float* __restrict__ src = (dir ? whh_b : whh_f) + (size_t)row * 256;
  float4 v = ((const float4*)src)[lane];
  float mx = fmaxf(fmaxf(fabsf(v.x), fabsf(v.y)), fmaxf(fabsf(v.z), fabsf(v.w)));
#pragma unroll
  for (int k = 32; k >= 1; k >>= 1) mx = fmaxf(mx, __shfl_xor(mx, k, 64));
  float inv = (mx > 0.f) ? __fdividef(127.f, mx) : 0.f;
  wq[(size_t)wave_g * 64 + lane] = pack4_(v, inv);
  if (lane == 0) wsc[wave_g] = (mx > 0.f) ? (mx / (127.f * 127.f)) : 0.f;
}

// ---------------------------------------------------------------------------
// Kernel A: projected embedding tables. M-tile 128.
// Stored at out[m*2048 + dir*1024 + u*4 + gate]  ([row][dir][unit][i,f,g,o]).
// ---------------------------------------------------------------------------
__global__ __launch_bounds__(256) void proj_gemm(
    const float* __restrict__ A, int rowsA, int Kdim, int col_off,
    const float* __restrict__ wf, const float* __restrict__ wb,
    const float* __restrict__ bf1, const float* __restrict__ bf2,
    const float* __restrict__ bb1, const float* __restrict__ bb2,
    __hip_bfloat16* __restrict__ out, int add_bias) {
  __shared__ __align__(16) __hip_bfloat16 As[128][40];
  __shared__ __align__(16) __hip_bfloat16 Bs[256][40];
  const int tid = threadIdx.x;
  const int m0 = blockIdx.x * 128, n0 = blockIdx.y * 256;
  const int lane = tid & 63, wave = tid >> 6;
  const int quad = lane >> 4, lm = lane & 15;
  float4v acc[2][16] = {};
  const int ksteps = (Kdim + 31) >> 5;
  const int r2 = tid >> 1, cbase = (tid & 1) << 4;
  const int rb = tid >> 4, cb = (tid & 15) * 2;
  for (int ks = 0; ks < ksteps; ++ks) {
    const int k0 = ks << 5;
#pragma unroll
    for (int e2 = 0; e2 < 8; ++e2) {
      int kk = k0 + cbase + 2 * e2;
      float b0 = 0.f, b1 = 0.f;
      if (m0 + r2 < rowsA && kk < Kdim) {
        float2 v = *(const float2*)(A + (size_t)(m0 + r2) * Kdim + kk);
        b0 = v.x;
        b1 = v.y;
      }
      As[r2][cbase + 2 * e2] = __float2bfloat16(b0);
      As[r2][cbase + 2 * e2 + 1] = __float2bfloat16(b1);
    }
#pragma unroll
    for (int j = 0; j < 16; ++j) {
      int n = n0 + rb + 16 * j;
      const float* __restrict__ wrow =
          (n < 1024) ? (wf + n * 450 + col_off) : (wb + (n - 1024) * 450 + col_off);
      int kk = k0 + cb;
      float b0 = 0.f, b1 = 0.f;
      if (kk < Kdim) {
        float2 v = *(const float2*)(wrow + kk);
        b0 = v.x;
        b1 = v.y;
      }
      Bs[rb + 16 * j][cb] = __float2bfloat16(b0);
      Bs[rb + 16 * j][cb + 1] = __float2bfloat16(b1);
    }
    __syncthreads();
    short8 af0 = *(const short8*)(&As[wave * 32 + lm][quad * 8]);
    short8 af1 = *(const short8*)(&As[wave * 32 + 16 + lm][quad * 8]);
#pragma unroll
    for (int t = 0; t < 16; ++t) {
      short8 bf = *(const short8*)(&Bs[t * 16 + lm][quad * 8]);
      acc[0][t] = __builtin_amdgcn_mfma_f32_16x16x32_bf16(af0, bf, acc[0][t], 0, 0, 0);
      acc[1][t] = __builtin_amdgcn_mfma_f32_16x16x32_bf16(af1, bf, acc[1][t], 0, 0, 0);
    }
    __syncthreads();
  }
#pragma unroll
  for (int mg = 0; mg < 2; ++mg) {
#pragma unroll
    for (int t = 0; t < 16; ++t) {
#pragma unroll
      for (int rr = 0; rr < 4; ++rr) {
        int m = m0 + wave * 32 + mg * 16 + quad * 4 + rr;
        int col = n0 + t * 16 + lm;
        if (m < rowsA) {
          float v = acc[mg][t][rr];
          if (add_bias)
            v += (col < 1024) ? (bf1[col] + bf2[col]) : (bb1[col - 1024] + bb2[col - 1024]);
          int dir = col >> 10, rq = col & 1023;
          int gate = rq >> 8, u = rq & 255;
          out[m * 2048 + dir * 1024 + u * 4 + gate] = __float2bfloat16(v);
        }
      }
    }
  }
}

// ---------------------------------------------------------------------------
// Kernel P: pre-sum pinyin + tag projections: pg[p*20+g] = pin[p] + tag[g].
// ---------------------------------------------------------------------------
__global__ __launch_bounds__(256) void pgsum_kernel(
    const __hip_bfloat16* __restrict__ pin, const __hip_bfloat16* __restrict__ tag,
    __hip_bfloat16* __restrict__ pg) {
  const int r = blockIdx.x;
  const int p = r / 20, g = r - p * 20;
  const int i = threadIdx.x;  // 256 threads x 8 bf16 = 2048
  const short8 va = *(const short8*)(pin + (size_t)p * 2048 + i * 8);
  const short8 vb = *(const short8*)(tag + (size_t)g * 2048 + i * 8);
  short8 vo;
#pragma unroll
  for (int j = 0; j < 8; ++j) {
    float a = __uint_as_float(((unsigned)(unsigned short)va[j]) << 16);
    float b = __uint_as_float(((unsigned)(unsigned short)vb[j]) << 16);
    __hip_bfloat16 o = __float2bfloat16(a + b);
    vo[j] = *(short*)&o;
  }
  *(short8*)(pg + (size_t)r * 2048 + i * 8) = vo;
}

// ---------------------------------------------------------------------------
// Kernel B (R22 champion, unchanged): 512 thr, 8 waves, rotated Bv preload,
// PG gathers, kZero acc-init, direct h store. lstm plateau ~590us at 2
// waves/SIMD (4-wave spills: R21; setprio null: R20; batching kills CU
// count: R16).
// ---------------------------------------------------------------------------
template <int USE_PG>
__global__ __launch_bounds__(512, 2) void lstm_kernel(
    const unsigned int* __restrict__ wq, const float* __restrict__ wsc,
    const int* __restrict__ x, const int* __restrict__ ptags, const int* __restrict__ gtags,
    const char* __restrict__ char_proj, const char* __restrict__ pin_proj,
    const char* __restrict__ tag_proj, const char* __restrict__ pg_proj,
    __hip_bfloat16* __restrict__ h_out) {
  extern __shared__ __align__(16) char smem[];
  char* hqb = smem;  // 2 x 272 (256 i8 h + pad)

  const int tid = threadIdx.x;
  const int w = tid >> 6, lane = tid & 63;
  const int quad = lane >> 4, lm = lane & 15;
  const int sel = lm >> 1;                // 0..7
  const int mt = sel >> 2, rr = sel & 3;  // runtime, used with literal idx only
  const int unit = w * 32 + mt * 16 + quad * 4 + rr;
  const int chain = blockIdx.x;
  const int dir = chain >> 7;
  const int b = chain & 127;
  const int boff = b * 512;

  if (tid < 34) ((uint4*)hqb)[tid] = make_uint4(0, 0, 0, 0);

  // weight fragments (MFMA A): Wf[g][m][kt], row = g*256 + w*32 + m*16 + lm
  const unsigned int* __restrict__ wqd = wq + (size_t)dir * 65536;
  int4v Wf[4][2][4];
#pragma unroll
  for (int g = 0; g < 4; ++g)
#pragma unroll
    for (int m = 0; m < 2; ++m) {
      const int row = g * 256 + w * 32 + m * 16 + lm;
#pragma unroll
      for (int kt = 0; kt < 4; ++kt)
        Wf[g][m][kt] = *(const int4v*)(wqd + row * 64 + kt * 16 + quad * 4);
    }
  float sc4[4];
#pragma unroll
  for (int g = 0; g < 4; ++g) sc4[g] = wsc[dir * 1024 + g * 256 + unit];
  __syncthreads();

  const int pre_off = dir * 2048 + unit * 8;  // byte offset into proj rows
  float cst = 0.f;
  int4v kZero = {0, 0, 0, 0};
  asm volatile("" : "+v"(kZero));  // keep materialized; block rematerialize-per-use

  // prologue: gathers for step 0; indices for step 1
  uint2 vc, vp, vg;
  int xn, pgn, pn, gn;
  {
    const int t0 = dir ? 511 : 0;
    int xc = x[boff + t0], pc = ptags[boff + t0], gc = gtags[boff + t0];
    vc = *(const uint2*)(char_proj + (size_t)xc * 4096 + pre_off);
    if (USE_PG) {
      vp = *(const uint2*)(pg_proj + (size_t)(pc * 20 + gc) * 4096 + pre_off);
    } else {
      vp = *(const uint2*)(pin_proj + (size_t)pc * 4096 + pre_off);
      vg = *(const uint2*)(tag_proj + (size_t)gc * 4096 + pre_off);
    }
    const int t1 = dir ? 510 : 1;
    xn = x[boff + t1];
    pn = ptags[boff + t1];
    gn = gtags[boff + t1];
    if (USE_PG) pgn = pn * 20 + gn;
  }

  // prologue: Bv(0) from buffer 0 (h(-1) = 0)
  int4v Bv[4];
#pragma unroll
  for (int kt = 0; kt < 4; ++kt)
    Bv[kt] = *(const int4v*)(hqb + kt * 64 + quad * 16);

  __hip_bfloat16* __restrict__ hrow = h_out + (size_t)chain * 512 * 256 + unit;

  for (int s = 0; s < 512; ++s) {
    const int nxt = (s & 1) ^ 1;
    const uint2 cv = vc, pv = vp, gv = vg;
    // issue gathers for step s+1 (xn/pgn hold its indices); prefetch s+2 idx
    vc = *(const uint2*)(char_proj + (size_t)xn * 4096 + pre_off);
    if (USE_PG) {
      vp = *(const uint2*)(pg_proj + (size_t)pgn * 4096 + pre_off);
    } else {
      vp = *(const uint2*)(pin_proj + (size_t)pn * 4096 + pre_off);
      vg = *(const uint2*)(tag_proj + (size_t)gn * 4096 + pre_off);
    }
    {
      const int k2 = (s + 2 < 512) ? s + 2 : 511;
      const int t2 = dir ? 511 - k2 : k2;
      xn = x[boff + t2];
      pn = ptags[boff + t2];
      gn = gtags[boff + t2];
      if (USE_PG) pgn = pn * 20 + gn;
    }

    // MFMA with preloaded Bv; kt=0 initializes acc from kZero (no mov burst)
    int4v acc[4][2];
#pragma unroll
    for (int g = 0; g < 4; ++g)
#pragma unroll
      for (int m = 0; m < 2; ++m)
        acc[g][m] = __builtin_amdgcn_mfma_i32_16x16x64_i8(Wf[g][m][0], Bv[0], kZero, 0, 0, 0);
#pragma unroll
    for (int kt = 1; kt < 4; ++kt) {
#pragma unroll
      for (int g = 0; g < 4; ++g)
#pragma unroll
        for (int m = 0; m < 2; ++m)
          acc[g][m] = __builtin_amdgcn_mfma_i32_16x16x64_i8(Wf[g][m][kt], Bv[kt], acc[g][m], 0, 0, 0);
    }

    // gate math: this lane's unit; acc component picked by (mt, rr)
    int ai = mt ? sel4_(acc[0][1], rr) : sel4_(acc[0][0], rr);
    int af = mt ? sel4_(acc[1][1], rr) : sel4_(acc[1][0], rr);
    int ag = mt ? sel4_(acc[2][1], rr) : sel4_(acc[2][0], rr);
    int ao = mt ? sel4_(acc[3][1], rr) : sel4_(acc[3][0], rr);
    float gi, gf, gg, go;
    if (USE_PG) {
      gi = bflo(cv.x) + bflo(pv.x) + (float)ai * sc4[0];
      gf = bfhi(cv.x) + bfhi(pv.x) + (float)af * sc4[1];
      gg = bflo(cv.y) + bflo(pv.y) + (float)ag * sc4[2];
      go = bfhi(cv.y) + bfhi(pv.y) + (float)ao * sc4[3];
    } else {
      gi = bflo(cv.x) + bflo(pv.x) + bflo(gv.x) + (float)ai * sc4[0];
      gf = bfhi(cv.x) + bfhi(pv.x) + bfhi(gv.x) + (float)af * sc4[1];
      gg = bflo(cv.y) + bflo(pv.y) + bflo(gv.y) + (float)ag * sc4[2];
      go = bfhi(cv.y) + bfhi(pv.y) + bfhi(gv.y) + (float)ao * sc4[3];
    }
    cst = sigmoidf_(gf) * cst + sigmoidf_(gi) * tanhf_(gg);
    float hval = sigmoidf_(go) * tanhf_(cst);
    if (!(lm & 1)) {  // even lm lanes cover all 256 units exactly once
      ((signed char*)hqb)[nxt * 272 + unit] = (signed char)(int)rintf(hval * 127.f);
    }
    barrier_lgkm();
    // read Bv for step s+1 IMMEDIATELY; the global h store below covers the
    // LDS latency before the next MFMA block consumes Bv
#pragma unroll
    for (int kt = 0; kt < 4; ++kt)
      Bv[kt] = *(const int4v*)(hqb + nxt * 272 + kt * 64 + quad * 16);
    if (!(lm & 1)) {
      const int tcur = dir ? 511 - s : s;
      hrow[(size_t)tcur * 256] = __float2bfloat16(hval);  // fire-and-forget
    }
  }
}

// ---------------------------------------------------------------------------
// Kernel EC (R23): fused emissions + CRF. One block per batch element.
// Phase 1: em[512][20] computed into LDS. w_out staged once as bf16 LDS
// [20][520]; A-fragments read DIRECTLY from h_glob into registers (no LDS
// staging, no per-kstep barriers); acc[8][2] in registers; ks loop outer so
// B-fragments load once per ks. MFMA sequence identical (same fragments,
// same ks order) to the old emis kernel -> bit-exact em.
// Phase 2/3: wave 0 runs score + serial forward from LDS em (same math as
// the old crf kernel; em reads are now ds_reads off the critical path; the
// 20-term dot uses 4 accumulator chains to halve the per-iter critical
// path). Saves: emis kernel + launch gap + em's 10MB HBM round trip.
// ---------------------------------------------------------------------------
__global__ __launch_bounds__(256) void emcrf_kernel(
    const __hip_bfloat16* __restrict__ h_glob, const float* __restrict__ w_out,
    const float* __restrict__ b_out, const int* __restrict__ y,
    const float* __restrict__ start_trans, const float* __restrict__ end_trans,
    const float* __restrict__ trans, float* __restrict__ partials) {
  extern __shared__ __align__(16) char smem2[];
  float* emL = (float*)smem2;                              // 512*20*4 = 40960
  __hip_bfloat16* wL = (__hip_bfloat16*)(smem2 + 40960);   // 20*520*2 = 20800

  const int b = blockIdx.x;
  const int tid = threadIdx.x;
  const int wave = tid >> 6, lane = tid & 63;
  const int quad = lane >> 4, lm = lane & 15;

  // stage w_out (f32 [20][512]) -> bf16 LDS [20][520]
  for (int i = tid; i < 10240; i += 256) {
    const int r = i >> 9, c = i & 511;
    wL[r * 520 + c] = __float2bfloat16(w_out[i]);
  }
  __syncthreads();

  // phase 1: em rows st*64 + wave*16 + {quad*4+rr}, cols t2*16+lm
  float bo[2];
#pragma unroll
  for (int t2 = 0; t2 < 2; ++t2) {
    const int col = t2 * 16 + lm;
    bo[t2] = (col < 20) ? b_out[col] : 0.f;
  }
  const int col0ok = lm < 16;           // t2=0 cols 0..15 always < 20
  const int col1ok = (16 + lm) < 20;    // t2=1 cols 16..19 only for lm<4
  float4v acc[8][2] = {};
  const int trow = wave * 16 + lm;  // A-row (within 64-row group) this lane loads
  for (int ks = 0; ks < 16; ++ks) {
    const int j0 = ks * 32;
    const int dirk = j0 >> 8, jin = j0 & 255;
    short8 bf0 = {}, bf1 = {};
    if (col0ok) bf0 = *(const short8*)(wL + lm * 520 + j0 + quad * 8);
    if (col1ok) bf1 = *(const short8*)(wL + (16 + lm) * 520 + j0 + quad * 8);
    const __hip_bfloat16* __restrict__ hbase =
        h_glob + ((size_t)(dirk * 128 + b) * 512 + trow) * 256 + jin + quad * 8;
#pragma unroll
    for (int st = 0; st < 8; ++st) {
      short8 af = *(const short8*)(hbase + (size_t)st * 64 * 256);
      acc[st][0] = __builtin_amdgcn_mfma_f32_16x16x32_bf16(af, bf0, acc[st][0], 0, 0, 0);
      acc[st][1] = __builtin_amdgcn_mfma_f32_16x16x32_bf16(af, bf1, acc[st][1], 0, 0, 0);
    }
  }
#pragma unroll
  for (int st = 0; st < 8; ++st) {
#pragma unroll
    for (int t2 = 0; t2 < 2; ++t2) {
      const int col = t2 * 16 + lm;
      if (col < 20) {
#pragma unroll
        for (int rr = 0; rr < 4; ++rr) {
          const int n = st * 64 + wave * 16 + quad * 4 + rr;
          emL[n * 20 + col] = acc[st][t2][rr] + bo[t2];
        }
      }
    }
  }
  __syncthreads();
  if (wave != 0) return;

  // phases 2+3: wave 0, em from LDS (identical math to the old crf kernel)
  const int jj = lane < 20 ? lane : 19;
  const bool act = lane < 20;
  const int* __restrict__ yb = y + b * 512;

  float s_part = 0.f;
#pragma unroll
  for (int i = 0; i < 8; ++i) {
    int t = lane + 64 * i;
    int yc = yb[t];
    float v = emL[t * 20 + yc];
    v += (t == 0) ? start_trans[yc] : trans[yb[t - 1] * 20 + yc];
    s_part += v;
  }
#pragma unroll
  for (int k = 32; k >= 1; k >>= 1) s_part += __shfl_xor(s_part, k, 64);
  float score = s_part + end_trans[yb[511]];

  float ET[20];
#pragma unroll
  for (int i = 0; i < 20; ++i) ET[i] = __expf(trans[i * 20 + jj]);
  float alpha = act ? (start_trans[jj] + emL[jj]) : -1e30f;
  float P = alpha;
#pragma unroll
  for (int k = 32; k >= 1; k >>= 1) P = fmaxf(P, __shfl_xor(P, k, 64));

  for (int t = 1; t < 512; ++t) {
    float eCur = emL[t * 20 + jj];  // LDS read, off the alpha critical path
    if ((t & 15) == 0) {
      P = alpha;
#pragma unroll
      for (int k = 32; k >= 1; k >>= 1) P = fmaxf(P, __shfl_xor(P, k, 64));
    }
    float ex = __expf(alpha - P);
    float s0 = 0.f, s1 = 0.f, s2 = 0.f, s3 = 0.f;  // 4 chains: path 40->20cy
#pragma unroll
    for (int i = 0; i < 20; i += 4) {
      float e0 = __int_as_float(__builtin_amdgcn_readlane(__float_as_int(ex), i));
      float e1 = __int_as_float(__builtin_amdgcn_readlane(__float_as_int(ex), i + 1));
      float e2 = __int_as_float(__builtin_amdgcn_readlane(__float_as_int(ex), i + 2));
      float e3 = __int_as_float(__builtin_amdgcn_readlane(__float_as_int(ex), i + 3));
      s0 = fmaf(e0, ET[i], s0);
      s1 = fmaf(e1, ET[i + 1], s1);
      s2 = fmaf(e2, ET[i + 2], s2);
      s3 = fmaf(e3, ET[i + 3], s3);
    }
    if (act) alpha = P + __logf((s0 + s1) + (s2 + s3)) + eCur;
  }
  float v = act ? (alpha + end_trans[jj]) : -1e30f;
  float Pz = v;
#pragma unroll
  for (int k = 32; k >= 1; k >>= 1) Pz = fmaxf(Pz, __shfl_xor(Pz, k, 64));
  float e2s = __expf(v - Pz);
#pragma unroll
  for (int k = 32; k >= 1; k >>= 1) e2s += __shfl_xor(e2s, k, 64);
  float logZ = Pz + __logf(e2s);
  if (lane == 0) partials[b] = logZ - score;
}

__global__ __launch_bounds__(128) void reduce_kernel(const float* __restrict__ partials,
                                                     float* __restrict__ out) {
  const int tid = threadIdx.x;
  float v = partials[tid];
#pragma unroll
  for (int k = 32; k >= 1; k >>= 1) v += __shfl_xor(v, k, 64);
  __shared__ float tmp[2];
  if ((tid & 63) == 0) tmp[tid >> 6] = v;
  __syncthreads();
  if (tid == 0) out[0] = tmp[0] + tmp[1];
}

// ---------------------------------------------------------------------------
extern "C" void kernel_launch(void* const* d_in, const int* in_sizes, int n_in,
                              void* d_out, int out_size, void* d_ws, size_t ws_size,
                              hipStream_t stream) {
  const int* x = (const int*)d_in[0];
  const int* y = (const int*)d_in[1];
  const int* pre_tags = (const int*)d_in[2];
  const int* pinyin_tags = (const int*)d_in[3];
  const float* char_emb = (const float*)d_in[5];
  const float* tag_emb = (const float*)d_in[6];
  const float* pinyin_emb = (const float*)d_in[7];
  const float* w_ih_f = (const float*)d_in[8];
  const float* w_hh_f = (const float*)d_in[9];
  const float* b_ih_f = (const float*)d_in[10];
  const float* b_hh_f = (const float*)d_in[11];
  const float* w_ih_b = (const float*)d_in[12];
  const float* w_hh_b = (const float*)d_in[13];
  const float* b_ih_b = (const float*)d_in[14];
  const float* b_hh_b = (const float*)d_in[15];
  const float* w_out = (const float*)d_in[16];
  const float* b_out = (const float*)d_in[17];
  const float* start_trans = (const float*)d_in[18];
  const float* end_trans = (const float*)d_in[19];
  const float* trans = (const float*)d_in[20];

  char* ws = (char*)d_ws;
  __hip_bfloat16* char_proj = (__hip_bfloat16*)(ws);            // 10002*2048*2 = 40968192
  __hip_bfloat16* pin_proj = (__hip_bfloat16*)(ws + 40968192);  // 500*2048*2  = 2048000
  __hip_bfloat16* tag_proj = (__hip_bfloat16*)(ws + 43016192);  // 20*2048*2   = 81920
  __hip_bfloat16* h_glob = (__hip_bfloat16*)(ws + 43098112);    // 2*128*512*256*2 = 67108864
  float* partials = (float*)(ws + 115449856);                   // 128*4
  // wq/wsc live in the former em region (unused since emis fused into crf)
  unsigned int* wq = (unsigned int*)(ws + 110206976);           // 2*1024*64*4 = 524288
  float* wsc = (float*)(ws + 110206976 + 524288);               // 2048*4
  // optional presummed pinyin+tag table (runtime-gated on ws_size)
  __hip_bfloat16* pg_proj = (__hip_bfloat16*)(ws + 115450368);  // 10000*2048*2 = 40960000
  const bool use_pg = ws_size >= (size_t)115450368 + 40960000;

  wquant_kernel<<<512, 256, 0, stream>>>(w_hh_f, w_hh_b, wq, wsc);

  proj_gemm<<<dim3(79, 8), 256, 0, stream>>>(char_emb, 10002, 300, 0, w_ih_f, w_ih_b,
                                             nullptr, nullptr, nullptr, nullptr, char_proj, 0);
  proj_gemm<<<dim3(4, 8), 256, 0, stream>>>(pinyin_emb, 500, 100, 300, w_ih_f, w_ih_b,
                                            nullptr, nullptr, nullptr, nullptr, pin_proj, 0);
  proj_gemm<<<dim3(1, 8), 256, 0, stream>>>(tag_emb, 20, 50, 400, w_ih_f, w_ih_b,
                                            b_ih_f, b_hh_f, b_ih_b, b_hh_b, tag_proj, 1);
  if (use_pg) pgsum_kernel<<<10000, 256, 0, stream>>>(pin_proj, tag_proj, pg_proj);

  const int lstm_lds = 1024;  // 544 hq double buffer (padded)
  if (use_pg) {
    hipFuncSetAttribute((const void*)lstm_kernel<1>, hipFuncAttributeMaxDynamicSharedMemorySize,
                        lstm_lds);
    lstm_kernel<1><<<256, 512, lstm_lds, stream>>>(wq, wsc, x, pinyin_tags, pre_tags,
                                                   (const char*)char_proj, (const char*)pin_proj,
                                                   (const char*)tag_proj, (const char*)pg_proj,
                                                   h_glob);
  } else {
    hipFuncSetAttribute((const void*)lstm_kernel<0>, hipFuncAttributeMaxDynamicSharedMemorySize,
                        lstm_lds);
    lstm_kernel<0><<<256, 512, lstm_lds, stream>>>(wq, wsc, x, pinyin_tags, pre_tags,
                                                   (const char*)char_proj, (const char*)pin_proj,
                                                   (const char*)tag_proj, (const char*)pg_proj,
                                                   h_glob);
  }

  const int emcrf_lds = 61760;  // 40960 emL + 20800 wL
  hipFuncSetAttribute((const void*)emcrf_kernel, hipFuncAttributeMaxDynamicSharedMemorySize,
                      emcrf_lds);
  emcrf_kernel<<<128, 256, emcrf_lds, stream>>>(h_glob, w_out, b_out, y, start_trans,
                                                end_trans, trans, partials);
  reduce_kernel<<<1, 128, 0, stream>>>(partials, (float*)d_out);
}